// Round 15
// baseline (58.122 us; speedup 1.0000x reference)
//
#include <hip/hip_runtime.h>
#include <hip/hip_bf16.h>

// RelPosSelfAttention on MI355X (gfx950)
// logits[b,n,h,w,p,q'] = qs·k[p,q'] + qs·rel_w[q'-w+47] + qs·rel_h[p-h+47]
// R16: R12 (41.5us, validated fences) + prefetch depth 1 -> 2 via THREE
// rotating 6-frag buffer pairs (same per-buffer LOADIT macro that is proven
// remat-free; R13's failure was 24-frag monolithic buffers). Each tile's
// loads now get ~2 COMPUTE regions of cover. Evidence: per-wave in-flight
// bytes correlates monotonically with speed (R5 0B:50.6, R10 4KB:48.6,
// R12 12KB:41.5); R9's waves x2 -> per-wave chain x2.13 = contended-queue
// latency signature, coverable only by depth.

typedef __attribute__((ext_vector_type(8))) short bf16x8;
typedef __attribute__((ext_vector_type(4))) float f32x4;

#define DEVFN __device__ __forceinline__

#if __has_builtin(__builtin_amdgcn_exp2f)
#define EXP2(x) __builtin_amdgcn_exp2f(x)
#else
#define EXP2(x) exp2f(x)
#endif

constexpr int H_ = 48, W_ = 48, D_ = 32;
constexpr int L_ = H_ * W_;          // 2304
constexpr int BN_ = 16;              // B*N

// ---- fast path geometry
constexpr int QB2 = 48;              // queries/block (3 waves x 16)
constexpr int QT2 = L_ / QB2;        // 48 q-tiles per bn
constexpr int NWG2 = BN_ * QT2;      // 768 = 3 * 256 CUs

// ---- ws layout (elements of u16)
constexpr size_t WE_Q = 0;                       // [16][2304][32]   row-major, pre-scaled
constexpr size_t WE_K = 1179648;                 // [16][24][6][64][8] permuted QK A-frag order
constexpr size_t WE_V = 2359296;                 // [16][24][6][64][8] V^T A-frag order
constexpr size_t WE_R = 3538944;                 // [2][6][64][8]    rel-table frag order
constexpr size_t WS_NEED = (WE_R + 2 * 6 * 64 * 8) * 2;  // 7,090,176 bytes

DEVFN unsigned short f2bf(float f) {
  unsigned u = __float_as_uint(f);               // manual RNE (fallback path only)
  return (unsigned short)((u + 0x7fffu + ((u >> 16) & 1u)) >> 16);
}
DEVFN unsigned pk2(float lo, float hi) {
  return (unsigned)f2bf(lo) | ((unsigned)f2bf(hi) << 16);
}
DEVFN unsigned pkcvt(float lo, float hi) {       // v_cvt_pk_bf16_f32 (RNE), lo in low 16
  __hip_bfloat162 h = __float22bfloat162_rn(make_float2(lo, hi));
  union { __hip_bfloat162 h2; unsigned u; } cv; cv.h2 = h;
  return cv.u;
}

template <int CTRL>
DEVFN float dppf(float x) {
  return __int_as_float(__builtin_amdgcn_update_dpp(0, __float_as_int(x), CTRL, 0xF, 0xF, true));
}
DEVFN float rowmax16(float x) {   // 16-lane DPP row reduce (fallback kernel)
  x = fmaxf(x, dppf<0x128>(x));
  x = fmaxf(x, dppf<0x124>(x));
  x = fmaxf(x, dppf<0x122>(x));
  x = fmaxf(x, dppf<0x121>(x));
  return x;
}
DEVFN float rowsum16(float x) {
  x += dppf<0x128>(x);
  x += dppf<0x124>(x);
  x += dppf<0x122>(x);
  x += dppf<0x121>(x);
  return x;
}

// ============================ pre-pass =====================================
// roles by blockIdx: [0,576) Q  [576,1152) K  [1152,1536) V  [1536,1539) R
__global__ __launch_bounds__(256)
void prep_kernel(const float* __restrict__ Q, const float* __restrict__ K,
                 const float* __restrict__ V, const float* __restrict__ RW,
                 const float* __restrict__ RH, unsigned short* __restrict__ ws)
{
  __shared__ __align__(16) float Vl[3072];               // one 96x32 V tile (V role)
  const int bid = blockIdx.x, tid = threadIdx.x;
  const float QS = 0.17677669529663687f * 1.4426950408889634f;  // D^-0.5 * log2(e)
  if (bid < 576) {
    size_t e = ((size_t)bid * 256 + tid) * 8;            // 8 elems/thread
    const float* s = Q + e;
    float4 a = *(const float4*)s, c = *(const float4*)(s + 4);
    uint4 wv;
    wv.x = pkcvt(a.x * QS, a.y * QS); wv.y = pkcvt(a.z * QS, a.w * QS);
    wv.z = pkcvt(c.x * QS, c.y * QS); wv.w = pkcvt(c.z * QS, c.w * QS);
    *(uint4*)(ws + WE_Q + e) = wv;
  } else if (bid < 1152) {
    // K: permuted rows so S^T D-frags concatenate into PV B-frags.
    // frag kb = kbp*2+f, slot s (=reader l15): physical key96 =
    //   kbp*32 + (s>>2)*8 + f*4 + (s&3)
    int idx = (bid - 576) * 256 + tid;                   // (bn*144 + it*6 + kb)*64 + lane
    int lane = idx & 63, t = idx >> 6;
    int l15 = lane & 15, lg = lane >> 4;
    int bn = t / 144, t16 = t % 144;
    int it = t16 / 6, kb = t16 % 6;
    int kbp = kb >> 1, f = kb & 1;
    int key96 = kbp * 32 + (l15 >> 2) * 8 + f * 4 + (l15 & 3);
    const float* s = K + ((size_t)(bn * L_ + it * 96 + key96) * D_ + lg * 8);
    float4 a = *(const float4*)s, c = *(const float4*)(s + 4);
    uint4 wv;
    wv.x = pkcvt(a.x, a.y); wv.y = pkcvt(a.z, a.w);
    wv.z = pkcvt(c.x, c.y); wv.w = pkcvt(c.z, c.w);
    *(uint4*)(ws + WE_K + (size_t)idx * 8) = wv;
  } else if (bid < 1536) {
    // V^T A-frags: frag f2 = kbp*2+half; lane holds
    //   V[key = kbp*32 + lg*8 + j][d = half*16 + l15], j=0..7
    const int tile = bid - 1152;                         // bn*24 + it
    const float* src = V + (size_t)tile * 96 * D_;
    #pragma unroll
    for (int u = 0; u < 3; ++u)
      ((float4*)Vl)[tid + u * 256] = ((const float4*)src)[tid + u * 256];
    __syncthreads();
    unsigned short* dst = ws + WE_V + (size_t)tile * 3072;
    #pragma unroll
    for (int u = 0; u < 2; ++u) {
      const int f2i = tid + u * 256;                     // frag-slot index 0..383
      if (f2i < 384) {
        const int f2 = f2i >> 6, lane = f2i & 63;
        const int l15 = lane & 15, lg = lane >> 4;
        const int kbp = f2 >> 1, half = f2 & 1;
        const int d = half * 16 + l15;
        float fv[8];
        #pragma unroll
        for (int j = 0; j < 8; ++j)
          fv[j] = Vl[(kbp * 32 + lg * 8 + j) * 32 + d];
        uint4 wv;
        wv.x = pkcvt(fv[0], fv[1]); wv.y = pkcvt(fv[2], fv[3]);
        wv.z = pkcvt(fv[4], fv[5]); wv.w = pkcvt(fv[6], fv[7]);
        *(uint4*)(dst + (size_t)f2i * 8) = wv;
      }
    }
  } else {
    int t = (bid - 1536) * 256 + tid;                    // tbl*384 + jb*64 + lane
    if (t < 768) {
      int tbl = t / 384, rem = t % 384, jb = rem / 64, lane = rem % 64;
      int l15 = lane & 15, lg = lane >> 4;
      int j = jb * 16 + l15;
      int jc = (j > 94) ? 94 : j;                        // clamp; j==95 discarded in main
      const float* s = (tbl ? RW : RH) + jc * D_ + lg * 8;
      float4 a = *(const float4*)s, c = *(const float4*)(s + 4);
      uint4 wv;
      wv.x = pkcvt(a.x, a.y); wv.y = pkcvt(a.z, a.w);
      wv.z = pkcvt(c.x, c.y); wv.w = pkcvt(c.z, c.w);
      *(uint4*)(ws + WE_R + (size_t)t * 8) = wv;
    }
  }
}

// ============================ main (fast) ==================================
__global__ __launch_bounds__(192, 3)
void relattn15(const unsigned short* __restrict__ ws, float* __restrict__ OUT)
{
  // Dedicated bias LDS only — no staging buffers, no barriers anywhere.
  __shared__ __align__(16) float BhT[48 * 50];
  __shared__ __align__(16) float BwT[48 * 52];

  const unsigned short* Qb = ws + WE_Q;
  const unsigned short* Kf = ws + WE_K;
  const unsigned short* Vf = ws + WE_V;
  const unsigned short* Rf = ws + WE_R;

  // XCD-aware swizzle (768 % 8 == 0 -> bijective); 96 blocks/XCD = 2 bn
  const int bid = blockIdx.x;
  const int wg  = (bid & 7) * (NWG2 / 8) + (bid >> 3);
  const int bn  = wg / QT2;
  const int qb  = (wg % QT2) * QB2;
  const int b   = bn >> 2, n = bn & 3;

  const int tid  = threadIdx.x;
  const int wave = tid >> 6;
  const int lane = tid & 63;
  const int l15  = lane & 15;
  const int lg   = lane >> 4;

  // Q frag (MFMA B operand after the swap): lane holds Q[q=l15][d=lg*8+j]
  const int qi = qb + wave * 16 + l15;
  const bf16x8 qfrag = *(const bf16x8*)(Qb + (size_t)(bn * L_ + qi) * D_ + lg * 8);

  const f32x4 z4 = {0.f, 0.f, 0.f, 0.f};

  // ---- bias tables via MFMA (rows wave-local; lgkmcnt orders write->read)
  #pragma unroll
  for (int jb = 0; jb < 6; ++jb) {
    bf16x8 rhf = *(const bf16x8*)(Rf + ((0 * 6 + jb) * 64 + lane) * 8);
    bf16x8 rwf = *(const bf16x8*)(Rf + ((1 * 6 + jb) * 64 + lane) * 8);
    f32x4 mh = __builtin_amdgcn_mfma_f32_16x16x32_bf16(qfrag, rhf, z4, 0, 0, 0);
    f32x4 mw = __builtin_amdgcn_mfma_f32_16x16x32_bf16(qfrag, rwf, z4, 0, 0, 0);
    const int j = jb * 16 + l15;
    if (j < 95) {
      #pragma unroll
      for (int r = 0; r < 4; ++r) {
        const int qg = qb + wave * 16 + lg * 4 + r;
        const int row = wave * 16 + lg * 4 + r;
        const int p  = j - 47 + qg / 48;
        if (p >= 0 && p < 48)  BhT[row * 50 + p]  = mh[r];
        const int ww = j - 47 + qg % 48;
        if (ww >= 0 && ww < 48) BwT[row * 52 + ww] = mw[r];
      }
    }
  }

  // Bw C-in rows live in LDS; per-kbp base pointers (all 16B aligned).
  // This lane's keys: key96 = kbp*32 + lg*8 + f*4 + r -> w' base = (lg*8+kbp*32)%48
  const int q52 = (wave * 16 + l15) * 52;
  const float* bwp0 = &BwT[q52 + lg * 8];
  const float* bwp1 = &BwT[q52 + ((lg < 2) ? (lg * 8 + 32) : (lg * 8 - 16))];
  const float* bwp2 = &BwT[q52 + lg * 8 + 16];

  const unsigned short* KfB = Kf + (size_t)bn * 24 * 3072 + (size_t)lane * 8;
  const unsigned short* VfB = Vf + (size_t)bn * 24 * 3072 + (size_t)lane * 8;

  f32x4 acc0 = z4, acc1 = z4;       // O^T accum: d = lg*4+r (+16), q = l15
  f32x4 accl = z4;                  // denominator accum: every row = l[q=l15]

  // constant ones A-frag for the denominator MFMA (A[i][k] = 1.0bf16)
  bf16x8 onesf;
  #pragma unroll
  for (int j = 0; j < 8; ++j) onesf[j] = (short)0x3F80;

  const float* bhrow = &BhT[(wave * 16 + l15) * 50];
  const bool lglo = (lg < 2);

  // THREE rotating buffer pairs -> prefetch depth 2 (2 COMPUTE regions cover)
  bf16x8 kfA[6], vfA[6], kfB[6], vfB[6], kfC[6], vfC[6];

#define LOADIT(kfX, vfX, itv) do {                                          \
    const int tc_ = ((itv) > 23) ? 23 : (itv);                              \
    const unsigned short* kt_ = KfB + (size_t)tc_ * 3072;                   \
    const unsigned short* vt_ = VfB + (size_t)tc_ * 3072;                   \
    _Pragma("unroll") for (int u = 0; u < 6; ++u)                           \
      kfX[u] = *(const bf16x8*)(kt_ + u * 512);                             \
    _Pragma("unroll") for (int u = 0; u < 6; ++u)                           \
      vfX[u] = *(const bf16x8*)(vt_ + u * 512);                             \
  } while (0)

#define COMPUTE(itv, kfX, vfX) do {                                         \
    const float2 bh2_ = *(const float2*)(bhrow + (itv) * 2);                \
    const float bhm_ = lglo ? bh2_.x : bh2_.y;                              \
    _Pragma("unroll") for (int kbp = 0; kbp < 3; ++kbp) {                   \
      const float* bwp_ = (kbp == 0) ? bwp0 : ((kbp == 1) ? bwp1 : bwp2);   \
      const float bhs_ = (kbp == 0) ? bh2_.x : ((kbp == 2) ? bh2_.y : bhm_);\
      f32x4 cin0 = *(const f32x4*)(bwp_);                                   \
      f32x4 cin1 = *(const f32x4*)(bwp_ + 4);                               \
      _Pragma("unroll") for (int r = 0; r < 4; ++r) {                       \
        cin0[r] += bhs_; cin1[r] += bhs_;                                   \
      }                                                                     \
      f32x4 s0 = __builtin_amdgcn_mfma_f32_16x16x32_bf16(kfX[kbp*2+0], qfrag, cin0, 0, 0, 0); \
      f32x4 s1 = __builtin_amdgcn_mfma_f32_16x16x32_bf16(kfX[kbp*2+1], qfrag, cin1, 0, 0, 0); \
      const float e0 = EXP2(s0[0]), e1 = EXP2(s0[1]);                       \
      const float e2 = EXP2(s0[2]), e3 = EXP2(s0[3]);                       \
      const float e4 = EXP2(s1[0]), e5 = EXP2(s1[1]);                       \
      const float e6 = EXP2(s1[2]), e7 = EXP2(s1[3]);                       \
      union { unsigned u[4]; bf16x8 v; } pf_;                               \
      pf_.u[0] = pkcvt(e0, e1); pf_.u[1] = pkcvt(e2, e3);                   \
      pf_.u[2] = pkcvt(e4, e5); pf_.u[3] = pkcvt(e6, e7);                   \
      acc0 = __builtin_amdgcn_mfma_f32_16x16x32_bf16(vfX[kbp*2+0], pf_.v, acc0, 0, 0, 0); \
      acc1 = __builtin_amdgcn_mfma_f32_16x16x32_bf16(vfX[kbp*2+1], pf_.v, acc1, 0, 0, 0); \
      accl = __builtin_amdgcn_mfma_f32_16x16x32_bf16(onesf, pf_.v, accl, 0, 0, 0); \
    }                                                                       \
  } while (0)

  LOADIT(kfA, vfA, 0);                           // prologue: depth-2 fill
  LOADIT(kfB, vfB, 1);
  for (int it3 = 0; it3 < 8; ++it3) {            // 3 tiles per iteration
    const int base = it3 * 3;
    __builtin_amdgcn_sched_barrier(0);
    LOADIT(kfC, vfC, base + 2);                  // used 2 regions later
    __builtin_amdgcn_sched_barrier(0);
    COMPUTE(base, kfA, vfA);
    __builtin_amdgcn_sched_barrier(0);
    LOADIT(kfA, vfA, base + 3);                  // used 2 regions later (clamped)
    __builtin_amdgcn_sched_barrier(0);
    COMPUTE(base + 1, kfB, vfB);
    __builtin_amdgcn_sched_barrier(0);
    LOADIT(kfB, vfB, base + 4);                  // used 2 regions later (clamped)
    __builtin_amdgcn_sched_barrier(0);
    COMPUTE(base + 2, kfC, vfC);
  }
#undef LOADIT
#undef COMPUTE

  // ---- epilogue: accl rows are all l[q=l15] (ones-A MFMA) -> no shuffles
  const float inv = __builtin_amdgcn_rcpf(accl[0]);
  const int ql = qb + wave * 16 + l15;
  const int hql = ql / 48, wql = ql % 48;
  float* op = OUT + ((size_t)(b * 48 + hql) * 48 + wql) * 128 + n * 32 + lg * 4;
  *(float4*)op        = make_float4(acc0[0] * inv, acc0[1] * inv, acc0[2] * inv, acc0[3] * inv);
  *(float4*)(op + 16) = make_float4(acc1[0] * inv, acc1[1] * inv, acc1[2] * inv, acc1[3] * inv);
}

// ===================== fallback (R1 kernel, ws-independent) ================
__global__ __launch_bounds__(256, 2)
void relattn_kernel(const float* __restrict__ Q, const float* __restrict__ K,
                    const float* __restrict__ V, const float* __restrict__ RW,
                    const float* __restrict__ RH, float* __restrict__ OUT)
{
  __shared__ __align__(16) unsigned short Klds[64][40];
  __shared__ __align__(16) unsigned       VT[32][36];
  __shared__ __align__(16) unsigned short Plds[4][16][72];
  __shared__ __align__(16) float          Bh[64][49];
  __shared__ __align__(16) float          Bw[64][49];

  const int bid = blockIdx.x;
  const int wg  = (bid & 7) * 72 + (bid >> 3);
  const int bn  = wg / 36;
  const int qb  = (wg % 36) * 64;
  const int b   = bn >> 2, n = bn & 3;

  const int tid  = threadIdx.x;
  const int wave = tid >> 6;
  const int lane = tid & 63;
  const int l15  = lane & 15;
  const int lg   = lane >> 4;

  const float QS = 0.17677669529663687f * 1.4426950408889634f;
  const int qi = qb + wave * 16 + l15;
  bf16x8 qfrag;
  {
    const float* qr = Q + ((bn * L_ + qi) * D_ + lg * 8);
    float4 a = *(const float4*)qr;
    float4 c = *(const float4*)(qr + 4);
    qfrag[0] = (short)f2bf(a.x * QS); qfrag[1] = (short)f2bf(a.y * QS);
    qfrag[2] = (short)f2bf(a.z * QS); qfrag[3] = (short)f2bf(a.w * QS);
    qfrag[4] = (short)f2bf(c.x * QS); qfrag[5] = (short)f2bf(c.y * QS);
    qfrag[6] = (short)f2bf(c.z * QS); qfrag[7] = (short)f2bf(c.w * QS);
  }
  const f32x4 z4 = {0.f, 0.f, 0.f, 0.f};
  #pragma unroll
  for (int jb = 0; jb < 6; ++jb) {
    const int j  = jb * 16 + l15;
    const int jc = (j > 94) ? 94 : j;
    bf16x8 rhf, rwf;
    {
      const float* rr = RH + jc * D_ + lg * 8;
      float4 a = *(const float4*)rr; float4 c = *(const float4*)(rr + 4);
      rhf[0] = (short)f2bf(a.x); rhf[1] = (short)f2bf(a.y);
      rhf[2] = (short)f2bf(a.z); rhf[3] = (short)f2bf(a.w);
      rhf[4] = (short)f2bf(c.x); rhf[5] = (short)f2bf(c.y);
      rhf[6] = (short)f2bf(c.z); rhf[7] = (short)f2bf(c.w);
      const float* rr2 = RW + jc * D_ + lg * 8;
      float4 a2 = *(const float4*)rr2; float4 c2 = *(const float4*)(rr2 + 4);
      rwf[0] = (short)f2bf(a2.x); rwf[1] = (short)f2bf(a2.y);
      rwf[2] = (short)f2bf(a2.z); rwf[3] = (short)f2bf(a2.w);
      rwf[4] = (short)f2bf(c2.x); rwf[5] = (short)f2bf(c2.y);
      rwf[6] = (short)f2bf(c2.z); rwf[7] = (short)f2bf(c2.w);
    }
    f32x4 mh = __builtin_amdgcn_mfma_f32_16x16x32_bf16(qfrag, rhf, z4, 0, 0, 0);
    f32x4 mw = __builtin_amdgcn_mfma_f32_16x16x32_bf16(qfrag, rwf, z4, 0, 0, 0);
    #pragma unroll
    for (int r = 0; r < 4; ++r) {
      const int qrow = lg * 4 + r;
      const int qg   = qb + wave * 16 + qrow;
      const int hqv  = qg / 48, wqv = qg % 48;
      if (j < 95) {
        const int p  = j - 47 + hqv;
        if (p >= 0 && p < 48) Bh[wave * 16 + qrow][p] = mh[r];
        const int ww = j - 47 + wqv;
        if (ww >= 0 && ww < 48) Bw[wave * 16 + qrow][ww] = mw[r];
      }
    }
  }
  float bw0[4], bw1[4], bw2[4];
  #pragma unroll
  for (int r = 0; r < 4; ++r) {
    bw0[r] = Bw[wave * 16 + lg * 4 + r][ 0 + l15];
    bw1[r] = Bw[wave * 16 + lg * 4 + r][16 + l15];
    bw2[r] = Bw[wave * 16 + lg * 4 + r][32 + l15];
  }
  f32x4 acc0 = z4, acc1 = z4;
  float m_r[4] = {-INFINITY, -INFINITY, -INFINITY, -INFINITY};
  float l_r[4] = {0.f, 0.f, 0.f, 0.f};
  const float* kbase = K + bn * L_ * D_;
  const float* vbase = V + bn * L_ * D_;
  for (int it = 0; it < 36; ++it) {
    const int kv0 = it * 64;
    __syncthreads();
    {
      const int r = tid >> 2, c = (tid & 3) * 8;
      const float* s = kbase + (kv0 + r) * D_ + c;
      float4 a = *(const float4*)s; float4 cc = *(const float4*)(s + 4);
      uint4 wv;
      wv.x = pk2(a.x, a.y);  wv.y = pk2(a.z, a.w);
      wv.z = pk2(cc.x, cc.y); wv.w = pk2(cc.z, cc.w);
      *(uint4*)&Klds[r][c] = wv;
    }
    {
      const int kp = tid >> 3, dg = tid & 7;
      const float* s0 = vbase + (kv0 + 2 * kp) * D_ + dg * 4;
      float4 a = *(const float4*)s0;
      float4 c = *(const float4*)(s0 + D_);
      VT[dg * 4 + 0][kp] = pk2(a.x, c.x);
      VT[dg * 4 + 1][kp] = pk2(a.y, c.y);
      VT[dg * 4 + 2][kp] = pk2(a.z, c.z);
      VT[dg * 4 + 3][kp] = pk2(a.w, c.w);
    }
    __syncthreads();
    f32x4 sacc[4];
    #pragma unroll
    for (int kb = 0; kb < 4; ++kb) {
      bf16x8 kf = *(const bf16x8*)&Klds[kb * 16 + l15][lg * 8];
      sacc[kb] = __builtin_amdgcn_mfma_f32_16x16x32_bf16(qfrag, kf, z4, 0, 0, 0);
    }
    const int p0   = kv0 / 48;
    const int tthr = (p0 + 1) * 48 - kv0;
    const int m0   = it % 3;
    float bh0[4], bh1[4];
    #pragma unroll
    for (int r = 0; r < 4; ++r) {
      bh0[r] = Bh[wave * 16 + lg * 4 + r][p0];
      bh1[r] = Bh[wave * 16 + lg * 4 + r][p0 + 1];
    }
    #pragma unroll
    for (int kb = 0; kb < 4; ++kb) {
      const bool hi = (kb * 16 + l15) >= tthr;
      int mm = m0 + kb; if (mm >= 3) mm -= 3; if (mm >= 3) mm -= 3;
      #pragma unroll
      for (int r = 0; r < 4; ++r) {
        const float bwv2 = (mm == 0) ? bw0[r] : ((mm == 1) ? bw1[r] : bw2[r]);
        sacc[kb][r] += (hi ? bh1[r] : bh0[r]) + bwv2;
      }
    }
    #pragma unroll
    for (int r = 0; r < 4; ++r) {
      float mx = fmaxf(fmaxf(sacc[0][r], sacc[1][r]), fmaxf(sacc[2][r], sacc[3][r]));
      mx = rowmax16(mx);
      const float mn = fmaxf(m_r[r], mx);
      const float sc = exp2f(m_r[r] - mn);
      m_r[r] = mn;
      acc0[r] *= sc; acc1[r] *= sc;
      const float pe0 = exp2f(sacc[0][r] - mn);
      const float pe1 = exp2f(sacc[1][r] - mn);
      const float pe2 = exp2f(sacc[2][r] - mn);
      const float pe3 = exp2f(sacc[3][r] - mn);
      const float rs = rowsum16(pe0 + pe1 + pe2 + pe3);
      l_r[r] = l_r[r] * sc + rs;
      const int prow = lg * 4 + r;
      Plds[wave][prow][ 0 + l15] = f2bf(pe0);
      Plds[wave][prow][16 + l15] = f2bf(pe1);
      Plds[wave][prow][32 + l15] = f2bf(pe2);
      Plds[wave][prow][48 + l15] = f2bf(pe3);
    }
    const unsigned short* VTu = (const unsigned short*)VT;
    #pragma unroll
    for (int s2 = 0; s2 < 2; ++s2) {
      bf16x8 a2 = *(const bf16x8*)&Plds[wave][l15][s2 * 32 + lg * 8];
      bf16x8 b0 = *(const bf16x8*)&VTu[( 0 + l15) * 72 + s2 * 32 + lg * 8];
      bf16x8 b1 = *(const bf16x8*)&VTu[(16 + l15) * 72 + s2 * 32 + lg * 8];
      acc0 = __builtin_amdgcn_mfma_f32_16x16x32_bf16(a2, b0, acc0, 0, 0, 0);
      acc1 = __builtin_amdgcn_mfma_f32_16x16x32_bf16(a2, b1, acc1, 0, 0, 0);
    }
  }
  #pragma unroll
  for (int r = 0; r < 4; ++r) {
    const int qg = qb + wave * 16 + lg * 4 + r;
    const int hqv = qg / 48, wqv = qg % 48;
    const float inv = __builtin_amdgcn_rcpf(l_r[r]);
    float* op = OUT + ((b * 48 + hqv) * 48 + wqv) * 128 + n * 32 + l15;
    op[0]  = acc0[r] * inv;
    op[16] = acc1[r] * inv;
  }
}

extern "C" void kernel_launch(void* const* d_in, const int* in_sizes, int n_in,
                              void* d_out, int out_size, void* d_ws, size_t ws_size,
                              hipStream_t stream) {
  const float* q  = (const float*)d_in[0];
  const float* k  = (const float*)d_in[1];
  const float* v  = (const float*)d_in[2];
  const float* rw = (const float*)d_in[3];
  const float* rh = (const float*)d_in[4];
  float* out = (float*)d_out;
  if (ws_size >= WS_NEED) {
    unsigned short* ws = (unsigned short*)d_ws;
    hipLaunchKernelGGL(prep_kernel, dim3(1539), dim3(256), 0, stream, q, k, v, rw, rh, ws);
    hipLaunchKernelGGL(relattn15, dim3(NWG2), dim3(192), 0, stream, ws, out);
  } else {
    hipLaunchKernelGGL(relattn_kernel, dim3(576), dim3(256), 0, stream, q, k, v, rw, rh, out);
  }
}

// Round 16
// 41.289 us; speedup vs baseline: 1.4077x; 1.4077x over previous
//
#include <hip/hip_runtime.h>
#include <hip/hip_bf16.h>

// RelPosSelfAttention on MI355X (gfx950)
// logits[b,n,h,w,p,q'] = qs·k[p,q'] + qs·rel_w[q'-w+47] + qs·rel_h[p-h+47]
// FINAL (= R12, validated 41.5us): swapped-operand QK^T keeps P in registers;
// bias_w as MFMA C-in from LDS + bias_h additive; denominator via ones-frag
// MFMA; fenced dual-buffer register prefetch (fences validated by R15
// ablation; depth-2 and wider regions falsified by remat in R13/R16).

typedef __attribute__((ext_vector_type(8))) short bf16x8;
typedef __attribute__((ext_vector_type(4))) float f32x4;

#define DEVFN __device__ __forceinline__

#if __has_builtin(__builtin_amdgcn_exp2f)
#define EXP2(x) __builtin_amdgcn_exp2f(x)
#else
#define EXP2(x) exp2f(x)
#endif

constexpr int H_ = 48, W_ = 48, D_ = 32;
constexpr int L_ = H_ * W_;          // 2304
constexpr int BN_ = 16;              // B*N

// ---- fast path geometry
constexpr int QB2 = 48;              // queries/block (3 waves x 16)
constexpr int IT2 = 24;              // 96-key tiles per bn
constexpr int QT2 = L_ / QB2;        // 48 q-tiles per bn
constexpr int NWG2 = BN_ * QT2;      // 768 = 3 * 256 CUs

// ---- ws layout (elements of u16)
constexpr size_t WE_Q = 0;                       // [16][2304][32]   row-major, pre-scaled
constexpr size_t WE_K = 1179648;                 // [16][24][6][64][8] permuted QK A-frag order
constexpr size_t WE_V = 2359296;                 // [16][24][6][64][8] V^T A-frag order
constexpr size_t WE_R = 3538944;                 // [2][6][64][8]    rel-table frag order
constexpr size_t WS_NEED = (WE_R + 2 * 6 * 64 * 8) * 2;  // 7,090,176 bytes

DEVFN unsigned short f2bf(float f) {
  unsigned u = __float_as_uint(f);               // manual RNE (fallback path only)
  return (unsigned short)((u + 0x7fffu + ((u >> 16) & 1u)) >> 16);
}
DEVFN unsigned pk2(float lo, float hi) {
  return (unsigned)f2bf(lo) | ((unsigned)f2bf(hi) << 16);
}
DEVFN unsigned pkcvt(float lo, float hi) {       // v_cvt_pk_bf16_f32 (RNE), lo in low 16
  __hip_bfloat162 h = __float22bfloat162_rn(make_float2(lo, hi));
  union { __hip_bfloat162 h2; unsigned u; } cv; cv.h2 = h;
  return cv.u;
}

template <int CTRL>
DEVFN float dppf(float x) {
  return __int_as_float(__builtin_amdgcn_update_dpp(0, __float_as_int(x), CTRL, 0xF, 0xF, true));
}
DEVFN float rowmax16(float x) {   // 16-lane DPP row reduce (fallback kernel)
  x = fmaxf(x, dppf<0x128>(x));
  x = fmaxf(x, dppf<0x124>(x));
  x = fmaxf(x, dppf<0x122>(x));
  x = fmaxf(x, dppf<0x121>(x));
  return x;
}
DEVFN float rowsum16(float x) {
  x += dppf<0x128>(x);
  x += dppf<0x124>(x);
  x += dppf<0x122>(x);
  x += dppf<0x121>(x);
  return x;
}

// ============================ pre-pass =====================================
// roles by blockIdx: [0,576) Q  [576,1152) K  [1152,1536) V  [1536,1539) R
__global__ __launch_bounds__(256)
void prep_kernel(const float* __restrict__ Q, const float* __restrict__ K,
                 const float* __restrict__ V, const float* __restrict__ RW,
                 const float* __restrict__ RH, unsigned short* __restrict__ ws)
{
  __shared__ __align__(16) float Vl[3072];               // one 96x32 V tile (V role)
  const int bid = blockIdx.x, tid = threadIdx.x;
  const float QS = 0.17677669529663687f * 1.4426950408889634f;  // D^-0.5 * log2(e)
  if (bid < 576) {
    size_t e = ((size_t)bid * 256 + tid) * 8;            // 8 elems/thread
    const float* s = Q + e;
    float4 a = *(const float4*)s, c = *(const float4*)(s + 4);
    uint4 wv;
    wv.x = pkcvt(a.x * QS, a.y * QS); wv.y = pkcvt(a.z * QS, a.w * QS);
    wv.z = pkcvt(c.x * QS, c.y * QS); wv.w = pkcvt(c.z * QS, c.w * QS);
    *(uint4*)(ws + WE_Q + e) = wv;
  } else if (bid < 1152) {
    // K: permuted rows so S^T D-frags concatenate into PV B-frags.
    // frag kb = kbp*2+f, slot s (=reader l15): physical key96 =
    //   kbp*32 + (s>>2)*8 + f*4 + (s&3)
    int idx = (bid - 576) * 256 + tid;                   // (bn*144 + it*6 + kb)*64 + lane
    int lane = idx & 63, t = idx >> 6;
    int l15 = lane & 15, lg = lane >> 4;
    int bn = t / 144, t16 = t % 144;
    int it = t16 / 6, kb = t16 % 6;
    int kbp = kb >> 1, f = kb & 1;
    int key96 = kbp * 32 + (l15 >> 2) * 8 + f * 4 + (l15 & 3);
    const float* s = K + ((size_t)(bn * L_ + it * 96 + key96) * D_ + lg * 8);
    float4 a = *(const float4*)s, c = *(const float4*)(s + 4);
    uint4 wv;
    wv.x = pkcvt(a.x, a.y); wv.y = pkcvt(a.z, a.w);
    wv.z = pkcvt(c.x, c.y); wv.w = pkcvt(c.z, c.w);
    *(uint4*)(ws + WE_K + (size_t)idx * 8) = wv;
  } else if (bid < 1536) {
    // V^T A-frags: frag f2 = kbp*2+half; lane holds
    //   V[key = kbp*32 + lg*8 + j][d = half*16 + l15], j=0..7
    const int tile = bid - 1152;                         // bn*24 + it
    const float* src = V + (size_t)tile * 96 * D_;
    #pragma unroll
    for (int u = 0; u < 3; ++u)
      ((float4*)Vl)[tid + u * 256] = ((const float4*)src)[tid + u * 256];
    __syncthreads();
    unsigned short* dst = ws + WE_V + (size_t)tile * 3072;
    #pragma unroll
    for (int u = 0; u < 2; ++u) {
      const int f2i = tid + u * 256;                     // frag-slot index 0..383
      if (f2i < 384) {
        const int f2 = f2i >> 6, lane = f2i & 63;
        const int l15 = lane & 15, lg = lane >> 4;
        const int kbp = f2 >> 1, half = f2 & 1;
        const int d = half * 16 + l15;
        float fv[8];
        #pragma unroll
        for (int j = 0; j < 8; ++j)
          fv[j] = Vl[(kbp * 32 + lg * 8 + j) * 32 + d];
        uint4 wv;
        wv.x = pkcvt(fv[0], fv[1]); wv.y = pkcvt(fv[2], fv[3]);
        wv.z = pkcvt(fv[4], fv[5]); wv.w = pkcvt(fv[6], fv[7]);
        *(uint4*)(dst + (size_t)f2i * 8) = wv;
      }
    }
  } else {
    int t = (bid - 1536) * 256 + tid;                    // tbl*384 + jb*64 + lane
    if (t < 768) {
      int tbl = t / 384, rem = t % 384, jb = rem / 64, lane = rem % 64;
      int l15 = lane & 15, lg = lane >> 4;
      int j = jb * 16 + l15;
      int jc = (j > 94) ? 94 : j;                        // clamp; j==95 discarded in main
      const float* s = (tbl ? RW : RH) + jc * D_ + lg * 8;
      float4 a = *(const float4*)s, c = *(const float4*)(s + 4);
      uint4 wv;
      wv.x = pkcvt(a.x, a.y); wv.y = pkcvt(a.z, a.w);
      wv.z = pkcvt(c.x, c.y); wv.w = pkcvt(c.z, c.w);
      *(uint4*)(ws + WE_R + (size_t)t * 8) = wv;
    }
  }
}

// ============================ main (fast) ==================================
__global__ __launch_bounds__(192, 3)
void relattn11(const unsigned short* __restrict__ ws, float* __restrict__ OUT)
{
  // Dedicated bias LDS only — no staging buffers, no barriers anywhere.
  __shared__ __align__(16) float BhT[48 * 50];
  __shared__ __align__(16) float BwT[48 * 52];

  const unsigned short* Qb = ws + WE_Q;
  const unsigned short* Kf = ws + WE_K;
  const unsigned short* Vf = ws + WE_V;
  const unsigned short* Rf = ws + WE_R;

  // XCD-aware swizzle (768 % 8 == 0 -> bijective); 96 blocks/XCD = 2 bn
  const int bid = blockIdx.x;
  const int wg  = (bid & 7) * (NWG2 / 8) + (bid >> 3);
  const int bn  = wg / QT2;
  const int qb  = (wg % QT2) * QB2;
  const int b   = bn >> 2, n = bn & 3;

  const int tid  = threadIdx.x;
  const int wave = tid >> 6;
  const int lane = tid & 63;
  const int l15  = lane & 15;
  const int lg   = lane >> 4;

  // Q frag (MFMA B operand after the swap): lane holds Q[q=l15][d=lg*8+j]
  const int qi = qb + wave * 16 + l15;
  const bf16x8 qfrag = *(const bf16x8*)(Qb + (size_t)(bn * L_ + qi) * D_ + lg * 8);

  const f32x4 z4 = {0.f, 0.f, 0.f, 0.f};

  // ---- bias tables via MFMA (rows wave-local; lgkmcnt orders write->read)
  #pragma unroll
  for (int jb = 0; jb < 6; ++jb) {
    bf16x8 rhf = *(const bf16x8*)(Rf + ((0 * 6 + jb) * 64 + lane) * 8);
    bf16x8 rwf = *(const bf16x8*)(Rf + ((1 * 6 + jb) * 64 + lane) * 8);
    f32x4 mh = __builtin_amdgcn_mfma_f32_16x16x32_bf16(qfrag, rhf, z4, 0, 0, 0);
    f32x4 mw = __builtin_amdgcn_mfma_f32_16x16x32_bf16(qfrag, rwf, z4, 0, 0, 0);
    const int j = jb * 16 + l15;
    if (j < 95) {
      #pragma unroll
      for (int r = 0; r < 4; ++r) {
        const int qg = qb + wave * 16 + lg * 4 + r;
        const int row = wave * 16 + lg * 4 + r;
        const int p  = j - 47 + qg / 48;
        if (p >= 0 && p < 48)  BhT[row * 50 + p]  = mh[r];
        const int ww = j - 47 + qg % 48;
        if (ww >= 0 && ww < 48) BwT[row * 52 + ww] = mw[r];
      }
    }
  }

  // Bw C-in rows live in LDS; per-kbp base pointers (all 16B aligned).
  // This lane's keys: key96 = kbp*32 + lg*8 + f*4 + r -> w' base = (lg*8+kbp*32)%48
  const int q52 = (wave * 16 + l15) * 52;
  const float* bwp0 = &BwT[q52 + lg * 8];
  const float* bwp1 = &BwT[q52 + ((lg < 2) ? (lg * 8 + 32) : (lg * 8 - 16))];
  const float* bwp2 = &BwT[q52 + lg * 8 + 16];

  const unsigned short* KfB = Kf + (size_t)bn * 24 * 3072 + (size_t)lane * 8;
  const unsigned short* VfB = Vf + (size_t)bn * 24 * 3072 + (size_t)lane * 8;

  f32x4 acc0 = z4, acc1 = z4;       // O^T accum: d = lg*4+r (+16), q = l15
  f32x4 accl = z4;                  // denominator accum: every row = l[q=l15]

  // constant ones A-frag for the denominator MFMA (A[i][k] = 1.0bf16)
  bf16x8 onesf;
  #pragma unroll
  for (int j = 0; j < 8; ++j) onesf[j] = (short)0x3F80;

  const float* bhrow = &BhT[(wave * 16 + l15) * 50];
  const bool lglo = (lg < 2);

  bf16x8 kfA[6], vfA[6], kfB[6], vfB[6];

#define LOADIT(kfX, vfX, itv) do {                                          \
    const unsigned short* kt_ = KfB + (size_t)(itv) * 3072;                 \
    const unsigned short* vt_ = VfB + (size_t)(itv) * 3072;                 \
    _Pragma("unroll") for (int u = 0; u < 6; ++u)                           \
      kfX[u] = *(const bf16x8*)(kt_ + u * 512);                             \
    _Pragma("unroll") for (int u = 0; u < 6; ++u)                           \
      vfX[u] = *(const bf16x8*)(vt_ + u * 512);                             \
  } while (0)

#define COMPUTE(itv, kfX, vfX) do {                                         \
    const float2 bh2_ = *(const float2*)(bhrow + (itv) * 2);                \
    const float bhm_ = lglo ? bh2_.x : bh2_.y;                              \
    _Pragma("unroll") for (int kbp = 0; kbp < 3; ++kbp) {                   \
      const float* bwp_ = (kbp == 0) ? bwp0 : ((kbp == 1) ? bwp1 : bwp2);   \
      const float bhs_ = (kbp == 0) ? bh2_.x : ((kbp == 2) ? bh2_.y : bhm_);\
      f32x4 cin0 = *(const f32x4*)(bwp_);                                   \
      f32x4 cin1 = *(const f32x4*)(bwp_ + 4);                               \
      _Pragma("unroll") for (int r = 0; r < 4; ++r) {                       \
        cin0[r] += bhs_; cin1[r] += bhs_;                                   \
      }                                                                     \
      f32x4 s0 = __builtin_amdgcn_mfma_f32_16x16x32_bf16(kfX[kbp*2+0], qfrag, cin0, 0, 0, 0); \
      f32x4 s1 = __builtin_amdgcn_mfma_f32_16x16x32_bf16(kfX[kbp*2+1], qfrag, cin1, 0, 0, 0); \
      const float e0 = EXP2(s0[0]), e1 = EXP2(s0[1]);                       \
      const float e2 = EXP2(s0[2]), e3 = EXP2(s0[3]);                       \
      const float e4 = EXP2(s1[0]), e5 = EXP2(s1[1]);                       \
      const float e6 = EXP2(s1[2]), e7 = EXP2(s1[3]);                       \
      union { unsigned u[4]; bf16x8 v; } pf_;                               \
      pf_.u[0] = pkcvt(e0, e1); pf_.u[1] = pkcvt(e2, e3);                   \
      pf_.u[2] = pkcvt(e4, e5); pf_.u[3] = pkcvt(e6, e7);                   \
      acc0 = __builtin_amdgcn_mfma_f32_16x16x32_bf16(vfX[kbp*2+0], pf_.v, acc0, 0, 0, 0); \
      acc1 = __builtin_amdgcn_mfma_f32_16x16x32_bf16(vfX[kbp*2+1], pf_.v, acc1, 0, 0, 0); \
      accl = __builtin_amdgcn_mfma_f32_16x16x32_bf16(onesf, pf_.v, accl, 0, 0, 0); \
    }                                                                       \
  } while (0)

  LOADIT(kfA, vfA, 0);                           // prologue
  for (int it2 = 0; it2 < IT2 / 2; ++it2) {
    const int itA = it2 * 2;
    __builtin_amdgcn_sched_barrier(0);
    LOADIT(kfB, vfB, itA + 1);                   // prefetch B (pinned at top)
    __builtin_amdgcn_sched_barrier(0);
    COMPUTE(itA, kfA, vfA);                      // overlap with B's flight
    __builtin_amdgcn_sched_barrier(0);
    LOADIT(kfA, vfA, itA + 2);                   // it=24 tail reads stay inside ws
    __builtin_amdgcn_sched_barrier(0);
    COMPUTE(itA + 1, kfB, vfB);
  }
#undef LOADIT
#undef COMPUTE

  // ---- epilogue: accl rows are all l[q=l15] (ones-A MFMA) -> no shuffles
  const float inv = __builtin_amdgcn_rcpf(accl[0]);
  const int ql = qb + wave * 16 + l15;
  const int hql = ql / 48, wql = ql % 48;
  float* op = OUT + ((size_t)(b * 48 + hql) * 48 + wql) * 128 + n * 32 + lg * 4;
  *(float4*)op        = make_float4(acc0[0] * inv, acc0[1] * inv, acc0[2] * inv, acc0[3] * inv);
  *(float4*)(op + 16) = make_float4(acc1[0] * inv, acc1[1] * inv, acc1[2] * inv, acc1[3] * inv);
}

// ===================== fallback (R1 kernel, ws-independent) ================
__global__ __launch_bounds__(256, 2)
void relattn_kernel(const float* __restrict__ Q, const float* __restrict__ K,
                    const float* __restrict__ V, const float* __restrict__ RW,
                    const float* __restrict__ RH, float* __restrict__ OUT)
{
  __shared__ __align__(16) unsigned short Klds[64][40];
  __shared__ __align__(16) unsigned       VT[32][36];
  __shared__ __align__(16) unsigned short Plds[4][16][72];
  __shared__ __align__(16) float          Bh[64][49];
  __shared__ __align__(16) float          Bw[64][49];

  const int bid = blockIdx.x;
  const int wg  = (bid & 7) * 72 + (bid >> 3);
  const int bn  = wg / 36;
  const int qb  = (wg % 36) * 64;
  const int b   = bn >> 2, n = bn & 3;

  const int tid  = threadIdx.x;
  const int wave = tid >> 6;
  const int lane = tid & 63;
  const int l15  = lane & 15;
  const int lg   = lane >> 4;

  const float QS = 0.17677669529663687f * 1.4426950408889634f;
  const int qi = qb + wave * 16 + l15;
  bf16x8 qfrag;
  {
    const float* qr = Q + ((bn * L_ + qi) * D_ + lg * 8);
    float4 a = *(const float4*)qr;
    float4 c = *(const float4*)(qr + 4);
    qfrag[0] = (short)f2bf(a.x * QS); qfrag[1] = (short)f2bf(a.y * QS);
    qfrag[2] = (short)f2bf(a.z * QS); qfrag[3] = (short)f2bf(a.w * QS);
    qfrag[4] = (short)f2bf(c.x * QS); qfrag[5] = (short)f2bf(c.y * QS);
    qfrag[6] = (short)f2bf(c.z * QS); qfrag[7] = (short)f2bf(c.w * QS);
  }
  const f32x4 z4 = {0.f, 0.f, 0.f, 0.f};
  #pragma unroll
  for (int jb = 0; jb < 6; ++jb) {
    const int j  = jb * 16 + l15;
    const int jc = (j > 94) ? 94 : j;
    bf16x8 rhf, rwf;
    {
      const float* rr = RH + jc * D_ + lg * 8;
      float4 a = *(const float4*)rr; float4 c = *(const float4*)(rr + 4);
      rhf[0] = (short)f2bf(a.x); rhf[1] = (short)f2bf(a.y);
      rhf[2] = (short)f2bf(a.z); rhf[3] = (short)f2bf(a.w);
      rhf[4] = (short)f2bf(c.x); rhf[5] = (short)f2bf(c.y);
      rhf[6] = (short)f2bf(c.z); rhf[7] = (short)f2bf(c.w);
      const float* rr2 = RW + jc * D_ + lg * 8;
      float4 a2 = *(const float4*)rr2; float4 c2 = *(const float4*)(rr2 + 4);
      rwf[0] = (short)f2bf(a2.x); rwf[1] = (short)f2bf(a2.y);
      rwf[2] = (short)f2bf(a2.z); rwf[3] = (short)f2bf(a2.w);
      rwf[4] = (short)f2bf(c2.x); rwf[5] = (short)f2bf(c2.y);
      rwf[6] = (short)f2bf(c2.z); rwf[7] = (short)f2bf(c2.w);
    }
    f32x4 mh = __builtin_amdgcn_mfma_f32_16x16x32_bf16(qfrag, rhf, z4, 0, 0, 0);
    f32x4 mw = __builtin_amdgcn_mfma_f32_16x16x32_bf16(qfrag, rwf, z4, 0, 0, 0);
    #pragma unroll
    for (int r = 0; r < 4; ++r) {
      const int qrow = lg * 4 + r;
      const int qg   = qb + wave * 16 + qrow;
      const int hqv  = qg / 48, wqv = qg % 48;
      if (j < 95) {
        const int p  = j - 47 + hqv;
        if (p >= 0 && p < 48) Bh[wave * 16 + qrow][p] = mh[r];
        const int ww = j - 47 + wqv;
        if (ww >= 0 && ww < 48) Bw[wave * 16 + qrow][ww] = mw[r];
      }
    }
  }
  float bw0[4], bw1[4], bw2[4];
  #pragma unroll
  for (int r = 0; r < 4; ++r) {
    bw0[r] = Bw[wave * 16 + lg * 4 + r][ 0 + l15];
    bw1[r] = Bw[wave * 16 + lg * 4 + r][16 + l15];
    bw2[r] = Bw[wave * 16 + lg * 4 + r][32 + l15];
  }
  f32x4 acc0 = z4, acc1 = z4;
  float m_r[4] = {-INFINITY, -INFINITY, -INFINITY, -INFINITY};
  float l_r[4] = {0.f, 0.f, 0.f, 0.f};
  const float* kbase = K + bn * L_ * D_;
  const float* vbase = V + bn * L_ * D_;
  for (int it = 0; it < 36; ++it) {
    const int kv0 = it * 64;
    __syncthreads();
    {
      const int r = tid >> 2, c = (tid & 3) * 8;
      const float* s = kbase + (kv0 + r) * D_ + c;
      float4 a = *(const float4*)s; float4 cc = *(const float4*)(s + 4);
      uint4 wv;
      wv.x = pk2(a.x, a.y);  wv.y = pk2(a.z, a.w);
      wv.z = pk2(cc.x, cc.y); wv.w = pk2(cc.z, cc.w);
      *(uint4*)&Klds[r][c] = wv;
    }
    {
      const int kp = tid >> 3, dg = tid & 7;
      const float* s0 = vbase + (kv0 + 2 * kp) * D_ + dg * 4;
      float4 a = *(const float4*)s0;
      float4 c = *(const float4*)(s0 + D_);
      VT[dg * 4 + 0][kp] = pk2(a.x, c.x);
      VT[dg * 4 + 1][kp] = pk2(a.y, c.y);
      VT[dg * 4 + 2][kp] = pk2(a.z, c.z);
      VT[dg * 4 + 3][kp] = pk2(a.w, c.w);
    }
    __syncthreads();
    f32x4 sacc[4];
    #pragma unroll
    for (int kb = 0; kb < 4; ++kb) {
      bf16x8 kf = *(const bf16x8*)&Klds[kb * 16 + l15][lg * 8];
      sacc[kb] = __builtin_amdgcn_mfma_f32_16x16x32_bf16(qfrag, kf, z4, 0, 0, 0);
    }
    const int p0   = kv0 / 48;
    const int tthr = (p0 + 1) * 48 - kv0;
    const int m0   = it % 3;
    float bh0[4], bh1[4];
    #pragma unroll
    for (int r = 0; r < 4; ++r) {
      bh0[r] = Bh[wave * 16 + lg * 4 + r][p0];
      bh1[r] = Bh[wave * 16 + lg * 4 + r][p0 + 1];
    }
    #pragma unroll
    for (int kb = 0; kb < 4; ++kb) {
      const bool hi = (kb * 16 + l15) >= tthr;
      int mm = m0 + kb; if (mm >= 3) mm -= 3; if (mm >= 3) mm -= 3;
      #pragma unroll
      for (int r = 0; r < 4; ++r) {
        const float bwv2 = (mm == 0) ? bw0[r] : ((mm == 1) ? bw1[r] : bw2[r]);
        sacc[kb][r] += (hi ? bh1[r] : bh0[r]) + bwv2;
      }
    }
    #pragma unroll
    for (int r = 0; r < 4; ++r) {
      float mx = fmaxf(fmaxf(sacc[0][r], sacc[1][r]), fmaxf(sacc[2][r], sacc[3][r]));
      mx = rowmax16(mx);
      const float mn = fmaxf(m_r[r], mx);
      const float sc = exp2f(m_r[r] - mn);
      m_r[r] = mn;
      acc0[r] *= sc; acc1[r] *= sc;
      const float pe0 = exp2f(sacc[0][r] - mn);
      const float pe1 = exp2f(sacc[1][r] - mn);
      const float pe2 = exp2f(sacc[2][r] - mn);
      const float pe3 = exp2f(sacc[3][r] - mn);
      const float rs = rowsum16(pe0 + pe1 + pe2 + pe3);
      l_r[r] = l_r[r] * sc + rs;
      const int prow = lg * 4 + r;
      Plds[wave][prow][ 0 + l15] = f2bf(pe0);
      Plds[wave][prow][16 + l15] = f2bf(pe1);
      Plds[wave][prow][32 + l15] = f2bf(pe2);
      Plds[wave][prow][48 + l15] = f2bf(pe3);
    }
    const unsigned short* VTu = (const unsigned short*)VT;
    #pragma unroll
    for (int s2 = 0; s2 < 2; ++s2) {
      bf16x8 a2 = *(const bf16x8*)&Plds[wave][l15][s2 * 32 + lg * 8];
      bf16x8 b0 = *(const bf16x8*)&VTu[( 0 + l15) * 72 + s2 * 32 + lg * 8];
      bf16x8 b1 = *(const bf16x8*)&VTu[(16 + l15) * 72 + s2 * 32 + lg * 8];
      acc0 = __builtin_amdgcn_mfma_f32_16x16x32_bf16(a2, b0, acc0, 0, 0, 0);
      acc1 = __builtin_amdgcn_mfma_f32_16x16x32_bf16(a2, b1, acc1, 0, 0, 0);
    }
  }
  #pragma unroll
  for (int r = 0; r < 4; ++r) {
    const int qg = qb + wave * 16 + lg * 4 + r;
    const int hqv = qg / 48, wqv = qg % 48;
    const float inv = __builtin_amdgcn_rcpf(l_r[r]);
    float* op = OUT + ((b * 48 + hqv) * 48 + wqv) * 128 + n * 32 + l15;
    op[0]  = acc0[r] * inv;
    op[16] = acc1[r] * inv;
  }
}

extern "C" void kernel_launch(void* const* d_in, const int* in_sizes, int n_in,
                              void* d_out, int out_size, void* d_ws, size_t ws_size,
                              hipStream_t stream) {
  const float* q  = (const float*)d_in[0];
  const float* k  = (const float*)d_in[1];
  const float* v  = (const float*)d_in[2];
  const float* rw = (const float*)d_in[3];
  const float* rh = (const float*)d_in[4];
  float* out = (float*)d_out;
  if (ws_size >= WS_NEED) {
    unsigned short* ws = (unsigned short*)d_ws;
    hipLaunchKernelGGL(prep_kernel, dim3(1539), dim3(256), 0, stream, q, k, v, rw, rh, ws);
    hipLaunchKernelGGL(relattn11, dim3(NWG2), dim3(192), 0, stream, ws, out);
  } else {
    hipLaunchKernelGGL(relattn_kernel, dim3(576), dim3(256), 0, stream, q, k, v, rw, rh, out);
  }
}